// Round 15
// baseline (117.312 us; speedup 1.0000x reference)
//
#include <hip/hip_runtime.h>

#define D1 96
#define GRID_VOX (D1 * D1 * D1)
#define CAP1 32   // per-voxel conv1 pairs (max 26 exact)
#define CAP2S 8   // per-(voxel,s) conv2 pairs (max 7 exact)
#define OS 68     // oT row stride in floats (bank-conflict pad, 16B aligned)

typedef __attribute__((ext_vector_type(8))) short short8_t;  // 8 bf16
typedef __attribute__((ext_vector_type(4))) float f32x4;

__device__ __forceinline__ unsigned short bf16rne(float x) {
    unsigned u = __float_as_uint(x);
    return (unsigned short)((u + 0x7FFF + ((u >> 16) & 1)) >> 16);
}
__device__ __forceinline__ void split2(float v, unsigned short& hi,
                                       unsigned short& lo) {
    hi = bf16rne(v);
    float hf = __uint_as_float((unsigned)hi << 16);
    lo = bf16rne(v - hf);
}
__device__ __forceinline__ float silu(float v) {
    return v / (1.f + __expf(-v));
}

// ---------------------------------------------------------------------------
// setup: blocks [0,432) zero grid; blocks [432,1474) pack MFMA B-fragments
// (bf16 hi/lo) and fold fp32 fixup weights.
// ---------------------------------------------------------------------------
__global__ void setup_kernel(const float* __restrict__ W1,
                             const float* __restrict__ W2,
                             int4* __restrict__ grid16,
                             unsigned short* __restrict__ Wpk1h,
                             unsigned short* __restrict__ Wpk1l,
                             unsigned short* __restrict__ Wpk2h,
                             unsigned short* __restrict__ Wpk2l,
                             float* __restrict__ W2e) {
    int b = blockIdx.x;
    if (b < 432) {
        grid16[b * 256 + threadIdx.x] = make_int4(0, 0, 0, 0);
        return;
    }
    int t = (b - 432) * 256 + threadIdx.x;
    if (t < 512) {  // conv1 B-fragments: W1[13] self tap
        int fid = t >> 6, l = t & 63;
        int kb = fid >> 2, c = fid & 3;
#pragma unroll
        for (int e = 0; e < 8; ++e) {
            int ci = kb * 32 + ((l >> 4) << 3) + e;
            int co = c * 16 + (l & 15);
            unsigned short hi, lo;
            split2(W1[13 * 4096 + ci * 64 + co], hi, lo);
            Wpk1h[(size_t)t * 8 + e] = hi;
            Wpk1l[(size_t)t * 8 + e] = lo;
        }
    } else if (t < 512 + 4096) {  // conv2 dense (self-parent fold) fragments
        int u = t - 512;
        int fid = u >> 6, l = u & 63;
        int s = fid >> 3, kb = (fid >> 2) & 1, c = fid & 3;
        int s0 = (s >> 2) & 1, s1 = (s >> 1) & 1, s2 = s & 1;
#pragma unroll
        for (int e = 0; e < 8; ++e) {
            int ci = kb * 32 + ((l >> 4) << 3) + e;
            int co = c * 16 + (l & 15);
            float sum = 0.f;
            for (int o0 = -s0; o0 <= 1 - s0; ++o0)
                for (int o1 = -s1; o1 <= 1 - s1; ++o1)
                    for (int o2 = -s2; o2 <= 1 - s2; ++o2) {
                        int k = (o0 + 1) * 9 + (o1 + 1) * 3 + (o2 + 1);
                        sum += W2[k * 4096 + ci * 64 + co];
                    }
            unsigned short hi, lo;
            split2(sum, hi, lo);
            Wpk2h[(size_t)u * 8 + e] = hi;
            Wpk2l[(size_t)u * 8 + e] = lo;
        }
    } else {  // W2e fp32 fixup weights
        int r = t - 4608;
        if (r >= 64 * 4096) return;
        int sd = r >> 12, e = r & 4095;
        int s = sd >> 3, d = sd & 7;
        int sa[3] = { (s >> 2) & 1, (s >> 1) & 1, s & 1 };
        int da[3] = { (d >> 2) & 1, (d >> 1) & 1, d & 1 };
        int lo_[3], hi_[3];
        for (int a = 0; a < 3; ++a) {
            int p = sa[a] - 1 + da[a];
            int l = 2 * p - sa[a];     if (l < -1) l = -1;
            int h = 2 * p + 1 - sa[a]; if (h > 1) h = 1;
            lo_[a] = l; hi_[a] = h;
        }
        float sum = 0.f;
        for (int o0 = lo_[0]; o0 <= hi_[0]; ++o0)
            for (int o1 = lo_[1]; o1 <= hi_[1]; ++o1)
                for (int o2 = lo_[2]; o2 <= hi_[2]; ++o2) {
                    int k = (o0 + 1) * 9 + (o1 + 1) * 3 + (o2 + 1);
                    sum += W2[k * 4096 + e];
                }
        W2e[(size_t)sd * 4096 + e] = sum;
    }
}

// ---------------------------------------------------------------------------
__global__ void scatter_grid_kernel(const int* __restrict__ coords,
                                    unsigned short* __restrict__ grid, int n) {
    int i = blockIdx.x * blockDim.x + threadIdx.x;
    if (i < n)
        grid[(coords[3 * i] * D1 + coords[3 * i + 1]) * D1 + coords[3 * i + 2]] =
            (unsigned short)(i + 1);
}

// ---------------------------------------------------------------------------
// Per-voxel pair builder (no atomics). conv1: j|(k<<17); conv2: j|(d<<17).
// ---------------------------------------------------------------------------
__global__ void build_pairs_kernel(const int* __restrict__ coords,
                                   const unsigned short* __restrict__ grid,
                                   int* __restrict__ c1, int* __restrict__ p1,
                                   int* __restrict__ c2s, int* __restrict__ p2s,
                                   int n) {
    int i = blockIdx.x * blockDim.x + threadIdx.x;
    if (i >= n) return;
    int c0 = coords[3 * i], cc1 = coords[3 * i + 1], cc2 = coords[3 * i + 2];

    int jv[27];
#pragma unroll
    for (int k = 0; k < 27; ++k) {
        int o0 = k / 9 - 1, o1 = (k / 3) % 3 - 1, o2 = k % 3 - 1;
        int x0 = c0 + o0, x1 = cc1 + o1, x2 = cc2 + o2;
        bool inb = (unsigned)x0 < D1 && (unsigned)x1 < D1 && (unsigned)x2 < D1;
        jv[k] = inb ? (int)grid[(x0 * D1 + x1) * D1 + x2] - 1 : -1;
    }

    int n1 = 0;
    int n2[8] = {0, 0, 0, 0, 0, 0, 0, 0};
#pragma unroll
    for (int k = 0; k < 27; ++k) {
        if (k == 13) continue;
        int j = jv[k];
        if (j < 0) continue;
        int o0 = k / 9 - 1, o1 = (k / 3) % 3 - 1, o2 = k % 3 - 1;
        p1[(size_t)i * CAP1 + n1] = j | (k << 17);
        ++n1;
#pragma unroll
        for (int s = 0; s < 8; ++s) {
            int d0 = o0 + 1 - ((s >> 2) & 1);
            int d1 = o1 + 1 - ((s >> 1) & 1);
            int d2 = o2 + 1 - (s & 1);
            if (((d0 | d1 | d2) & ~1) == 0) {
                int d = (d0 << 2) | (d1 << 1) | d2;
                p2s[((size_t)i * 8 + s) * CAP2S + n2[s]] = j | (d << 17);
                ++n2[s];
            }
        }
    }
    c1[i] = n1;
#pragma unroll
    for (int s = 0; s < 8; ++s) c2s[i * 8 + s] = n2[s];
}

// ---------------------------------------------------------------------------
__device__ __forceinline__ void load_split_A(const float* __restrict__ src,
                                             int arow, int lane, short8_t& ah0,
                                             short8_t& al0, short8_t& ah1,
                                             short8_t& al1) {
    const float* ap = src + (size_t)arow * 64 + ((lane >> 4) << 3);
    f32x4 a0 = *(const f32x4*)(ap);
    f32x4 a1 = *(const f32x4*)(ap + 4);
    f32x4 a2 = *(const f32x4*)(ap + 32);
    f32x4 a3 = *(const f32x4*)(ap + 36);
#pragma unroll
    for (int e = 0; e < 4; ++e) {
        unsigned short hh, ll;
        split2(a0[e], hh, ll); ah0[e] = (short)hh; al0[e] = (short)ll;
        split2(a1[e], hh, ll); ah0[4 + e] = (short)hh; al0[4 + e] = (short)ll;
        split2(a2[e], hh, ll); ah1[e] = (short)hh; al1[e] = (short)ll;
        split2(a3[e], hh, ll); ah1[4 + e] = (short)hh; al1[4 + e] = (short)ll;
    }
}

// ---------------------------------------------------------------------------
// wave w: rows [16w,16w+16) x 64 cols, 24 MFMAs (hi/lo), +bias -> oT (stride OS).
// ---------------------------------------------------------------------------
__device__ __forceinline__ void dense_mfma(const short8_t ah0, const short8_t al0,
                                           const short8_t ah1, const short8_t al1,
                                           const short8_t* __restrict__ Bh,
                                           const short8_t* __restrict__ Bl,
                                           const float* __restrict__ bias,
                                           float* __restrict__ oT, int w,
                                           int lane) {
#pragma unroll 1
    for (int c = 0; c < 4; ++c) {
        short8_t bh0 = Bh[c * 64 + lane];
        short8_t bl0 = Bl[c * 64 + lane];
        short8_t bh1 = Bh[(4 + c) * 64 + lane];
        short8_t bl1 = Bl[(4 + c) * 64 + lane];
        f32x4 acc = {0.f, 0.f, 0.f, 0.f};
        acc = __builtin_amdgcn_mfma_f32_16x16x32_bf16(ah0, bh0, acc, 0, 0, 0);
        acc = __builtin_amdgcn_mfma_f32_16x16x32_bf16(al0, bh0, acc, 0, 0, 0);
        acc = __builtin_amdgcn_mfma_f32_16x16x32_bf16(ah0, bl0, acc, 0, 0, 0);
        acc = __builtin_amdgcn_mfma_f32_16x16x32_bf16(ah1, bh1, acc, 0, 0, 0);
        acc = __builtin_amdgcn_mfma_f32_16x16x32_bf16(al1, bh1, acc, 0, 0, 0);
        acc = __builtin_amdgcn_mfma_f32_16x16x32_bf16(ah1, bl1, acc, 0, 0, 0);
        int col = c * 16 + (lane & 15);
        float bb = bias[col];
#pragma unroll
        for (int r = 0; r < 4; ++r) {
            int row = w * 16 + ((lane >> 4) << 2) + r;
            oT[row * OS + col] = acc[r] + bb;
        }
    }
}

// wave-scan helper (t<64): counts -> excl prefix + total, stored in LDS
__device__ __forceinline__ void scan64(int cnt, int lane, int* pfxs, int* cnts,
                                       int* nps) {
    int val = cnt;
#pragma unroll
    for (int off = 1; off < 64; off <<= 1) {
        int v2 = __shfl_up(val, off);
        if (lane >= off) val += v2;
    }
    pfxs[lane] = val - cnt;
    cnts[lane] = cnt;
    if (lane == 63) nps[0] = val;
}

// ---------------------------------------------------------------------------
// Barrier-free per-wave fixup loop (round-14 structure, oT stride OS).
// ---------------------------------------------------------------------------
__device__ __forceinline__ void fixup_loop(const float* __restrict__ src,
                                           const float* __restrict__ Wbase,
                                           const int* __restrict__ pl, int np,
                                           float fsc[4][2][64],
                                           float* __restrict__ oT, int w,
                                           int lane) {
    int it = 0;
#pragma unroll 1
    for (int p = w; p < np; p += 4, ++it) {
        int e = pl[p];
        int j = e & 0x1FFFF, tag = (e >> 17) & 31, row = (e >> 23) & 63;
        float fv = src[(size_t)j * 64 + lane];  // coalesced 256B row
        int buf = it & 1;
        fsc[w][buf][lane] = fv;
        const float* wk = Wbase + (size_t)tag * 4096;  // [ci][co]
        float a0 = 0.f, a1 = 0.f, a2 = 0.f, a3 = 0.f;
#pragma unroll
        for (int c4 = 0; c4 < 16; ++c4) {
            f32x4 fb = *(f32x4*)&fsc[w][buf][c4 * 4];  // ds broadcast
            a0 += fb[0] * wk[(c4 * 4 + 0) * 64 + lane];
            a1 += fb[1] * wk[(c4 * 4 + 1) * 64 + lane];
            a2 += fb[2] * wk[(c4 * 4 + 2) * 64 + lane];
            a3 += fb[3] * wk[(c4 * 4 + 3) * 64 + lane];
        }
        atomicAdd(&oT[row * OS + lane], (a0 + a1) + (a2 + a3));
    }
}

// ---------------------------------------------------------------------------
// conv1 fused: dense MFMA ∥ scan -> compact -> barrier-free fixups -> SiLU.
// ---------------------------------------------------------------------------
__global__ __launch_bounds__(256) void conv1_fused_kernel(
    const float* __restrict__ feats, const float* __restrict__ W1,
    const unsigned short* __restrict__ Wpk1h,
    const unsigned short* __restrict__ Wpk1l, const float* __restrict__ b1,
    const int* __restrict__ c1, const int* __restrict__ p1,
    float* __restrict__ h, int n) {
    __shared__ __align__(16) float oT[64 * OS];
    __shared__ __align__(16) float fsc[4][2][64];
    __shared__ int pl[1664];
    __shared__ int pfxs[64], cnts_s[64], nps[1];
    int base = blockIdx.x * 64;
    int t = threadIdx.x, w = t >> 6, lane = t & 63;

    if (t < 64) {
        int cnt = (base + lane < n) ? c1[base + lane] : 0;
        scan64(cnt, lane, pfxs, cnts_s, nps);
    }

    int arow = base + w * 16 + (lane & 15);
    if (arow >= n) arow = n - 1;
    short8_t ah0, al0, ah1, al1;
    load_split_A(feats, arow, lane, ah0, al0, ah1, al1);
    dense_mfma(ah0, al0, ah1, al1, (const short8_t*)Wpk1h,
               (const short8_t*)Wpk1l, b1, oT, w, lane);
    __syncthreads();

    {   // parallel compaction: 4 threads per row
        int row = t & 63, e0 = t >> 6;
        int cr = cnts_s[row], pf = pfxs[row];
        for (int e = e0; e < cr; e += 4)
            pl[pf + e] = p1[(size_t)(base + row) * CAP1 + e] | (row << 23);
    }
    __syncthreads();

    fixup_loop(feats, W1, pl, nps[0], fsc, oT, w, lane);
    __syncthreads();

    {   // SiLU + coalesced store (h is re-read by conv2: keep temporal)
        int r = t >> 2, q0 = (t & 3) * 16;
        if (base + r < n) {
#pragma unroll
            for (int jj = 0; jj < 4; ++jj) {
                f32x4 v = *(f32x4*)&oT[r * OS + q0 + jj * 4];
#pragma unroll
                for (int u = 0; u < 4; ++u) v[u] = silu(v[u]);
                *(f32x4*)&h[(size_t)(base + r) * 64 + q0 + jj * 4] = v;
            }
        }
    }
}

// ---------------------------------------------------------------------------
// conv2 fused: 1D grid 2560 = 8 children x 320 tiles; idx = s*320 + T so all
// 8 children of tile T share idx%8 -> same XCD L2 caches the h-tile once.
// ---------------------------------------------------------------------------
__global__ __launch_bounds__(256) void conv2_fused_kernel(
    const float* __restrict__ h, const unsigned short* __restrict__ Wpk2h,
    const unsigned short* __restrict__ Wpk2l, const float* __restrict__ W2e,
    const float* __restrict__ b2, const int* __restrict__ c2s,
    const int* __restrict__ p2s, float* __restrict__ out, int n) {
    __shared__ __align__(16) float oT[64 * OS];
    __shared__ __align__(16) float fsc[4][2][64];
    __shared__ int pl[448];
    __shared__ int pfxs[64], cnts_s[64], nps[1];
    int s = blockIdx.x / 320, T = blockIdx.x % 320;
    int base = T * 64;
    if (base >= n) return;
    int t = threadIdx.x, w = t >> 6, lane = t & 63;

    if (t < 64) {
        int cnt = (base + lane < n) ? c2s[(size_t)(base + lane) * 8 + s] : 0;
        scan64(cnt, lane, pfxs, cnts_s, nps);
    }

    int arow = base + w * 16 + (lane & 15);
    if (arow >= n) arow = n - 1;
    short8_t ah0, al0, ah1, al1;
    load_split_A(h, arow, lane, ah0, al0, ah1, al1);
    dense_mfma(ah0, al0, ah1, al1,
               (const short8_t*)Wpk2h + (size_t)s * 8 * 64,
               (const short8_t*)Wpk2l + (size_t)s * 8 * 64, b2, oT, w, lane);
    __syncthreads();

    {   // parallel compaction
        int row = t & 63, e0 = t >> 6;
        int cr = cnts_s[row], pf = pfxs[row];
        for (int e = e0; e < cr; e += 4)
            pl[pf + e] =
                p2s[((size_t)(base + row) * 8 + s) * CAP2S + e] | (row << 23);
    }
    __syncthreads();

    fixup_loop(h, W2e + (size_t)s * 8 * 4096, pl, nps[0], fsc, oT, w, lane);
    __syncthreads();

    {   // SiLU + non-temporal store (out never re-read; keep h hot in L2)
        int r = t >> 2, q0 = (t & 3) * 16;
        if (base + r < n) {
#pragma unroll
            for (int jj = 0; jj < 4; ++jj) {
                f32x4 v = *(f32x4*)&oT[r * OS + q0 + jj * 4];
#pragma unroll
                for (int u = 0; u < 4; ++u) v[u] = silu(v[u]);
                __builtin_nontemporal_store(
                    v, (f32x4*)&out[((size_t)(base + r) * 8 + s) * 64 + q0 +
                                    jj * 4]);
            }
        }
    }
}

// ---------------------------------------------------------------------------
extern "C" void kernel_launch(void* const* d_in, const int* in_sizes, int n_in,
                              void* d_out, int out_size, void* d_ws,
                              size_t ws_size, hipStream_t stream) {
    const int* coords = (const int*)d_in[0];
    const float* feats = (const float*)d_in[1];
    const float* W1 = (const float*)d_in[2];
    const float* b1 = (const float*)d_in[3];
    const float* W2 = (const float*)d_in[4];
    const float* b2 = (const float*)d_in[5];
    float* out = (float*)d_out;

    int n = in_sizes[0] / 3;  // 20000
    int nblk = (n + 63) / 64; // 313

    char* ws = (char*)d_ws;
    size_t off = 0;
    auto alloc = [&](size_t bytes) {
        size_t o = off;
        off = (off + bytes + 255) & ~(size_t)255;
        return o;
    };
    unsigned short* grid1 = (unsigned short*)(ws + alloc((size_t)GRID_VOX * 2));
    float* h      = (float*)(ws + alloc((size_t)n * 64 * 4));     // 5.12 MB
    float* W2e    = (float*)(ws + alloc(64 * 4096 * 4));          // 1 MB
    unsigned short* Wpk1h = (unsigned short*)(ws + alloc(512 * 8 * 2));
    unsigned short* Wpk1l = (unsigned short*)(ws + alloc(512 * 8 * 2));
    unsigned short* Wpk2h = (unsigned short*)(ws + alloc(4096 * 8 * 2));
    unsigned short* Wpk2l = (unsigned short*)(ws + alloc(4096 * 8 * 2));
    int*   c1     = (int*)(ws + alloc((size_t)n * 9 * 4));        // c1[n]+c2s[8n]
    int*   c2s    = c1 + n;
    int*   p1     = (int*)(ws + alloc((size_t)n * CAP1 * 4));     // 2.56 MB
    int*   p2s    = (int*)(ws + alloc((size_t)n * 8 * CAP2S * 4)); // 5.12 MB

    setup_kernel<<<1474, 256, 0, stream>>>(W1, W2, (int4*)grid1, Wpk1h, Wpk1l,
                                           Wpk2h, Wpk2l, W2e);
    scatter_grid_kernel<<<(n + 255) / 256, 256, 0, stream>>>(coords, grid1, n);
    build_pairs_kernel<<<(n + 255) / 256, 256, 0, stream>>>(
        coords, grid1, c1, p1, c2s, p2s, n);

    conv1_fused_kernel<<<nblk, 256, 0, stream>>>(feats, W1, Wpk1h, Wpk1l, b1,
                                                 c1, p1, h, n);
    conv2_fused_kernel<<<8 * 320, 256, 0, stream>>>(
        h, Wpk2h, Wpk2l, W2e, b2, c2s, p2s, out, n);
}

// Round 16
// 109.268 us; speedup vs baseline: 1.0736x; 1.0736x over previous
//
#include <hip/hip_runtime.h>

#define D1 96
#define GRID_VOX (D1 * D1 * D1)
#define OS 68  // oT row stride in floats (bank-conflict pad, 16B aligned)

typedef __attribute__((ext_vector_type(8))) short short8_t;  // 8 bf16
typedef __attribute__((ext_vector_type(4))) float f32x4;
typedef unsigned short ushort_t;

__device__ __forceinline__ unsigned short bf16rne(float x) {
    unsigned u = __float_as_uint(x);
    return (unsigned short)((u + 0x7FFF + ((u >> 16) & 1)) >> 16);
}
__device__ __forceinline__ void split2(float v, unsigned short& hi,
                                       unsigned short& lo) {
    hi = bf16rne(v);
    float hf = __uint_as_float((unsigned)hi << 16);
    lo = bf16rne(v - hf);
}
__device__ __forceinline__ float silu(float v) {
    return v / (1.f + __expf(-v));
}

// ---------------------------------------------------------------------------
// setup: [0,432) zero grid; [432,432+nzb) zero j-tables; rest pack bf16 hi/lo
// MFMA B-fragments for all 27 conv1 taps and all 64 conv2 (s,d) folds.
// Fragment layout (verified rounds 7-15): fid=kb*4+c, elem e:
//   ci = kb*32 + (l>>4)*8 + e, co = c*16 + (l&15)
// ---------------------------------------------------------------------------
__global__ void setup_kernel(const float* __restrict__ W1,
                             const float* __restrict__ W2,
                             int4* __restrict__ grid16,
                             int4* __restrict__ jtz, int njt16, int nzb,
                             unsigned short* __restrict__ Wpk1h,
                             unsigned short* __restrict__ Wpk1l,
                             unsigned short* __restrict__ Wpk2h,
                             unsigned short* __restrict__ Wpk2l) {
    int b = blockIdx.x;
    if (b < 432) {
        grid16[b * 256 + threadIdx.x] = make_int4(0, 0, 0, 0);
        return;
    }
    if (b < 432 + nzb) {
        int idx = (b - 432) * 256 + threadIdx.x;
        if (idx < njt16) jtz[idx] = make_int4(0, 0, 0, 0);
        return;
    }
    int t = (b - 432 - nzb) * 256 + threadIdx.x;
    if (t < 27 * 512) {  // conv1 B-fragments for all taps k
        int k = t >> 9, r = t & 511;
        int fid = r >> 6, l = r & 63;
        int kb = fid >> 2, c = fid & 3;
#pragma unroll
        for (int e = 0; e < 8; ++e) {
            int ci = kb * 32 + ((l >> 4) << 3) + e;
            int co = c * 16 + (l & 15);
            unsigned short hi, lo;
            split2(W1[(size_t)k * 4096 + ci * 64 + co], hi, lo);
            Wpk1h[(size_t)t * 8 + e] = hi;
            Wpk1l[(size_t)t * 8 + e] = lo;
        }
    } else if (t < 27 * 512 + 64 * 512) {  // conv2 folded fragments, all (s,d)
        int u = t - 27 * 512;
        int mat = u >> 9, r = u & 511;
        int fid = r >> 6, l = r & 63;
        int s = mat >> 3, d = mat & 7;
        int kb = fid >> 2, c = fid & 3;
        int sa[3] = { (s >> 2) & 1, (s >> 1) & 1, s & 1 };
        int da[3] = { (d >> 2) & 1, (d >> 1) & 1, d & 1 };
        int lo_[3], hi_[3];
        for (int a = 0; a < 3; ++a) {
            int p = sa[a] - 1 + da[a];
            int ll = 2 * p - sa[a];     if (ll < -1) ll = -1;
            int hh = 2 * p + 1 - sa[a]; if (hh > 1) hh = 1;
            lo_[a] = ll; hi_[a] = hh;
        }
#pragma unroll
        for (int e = 0; e < 8; ++e) {
            int ci = kb * 32 + ((l >> 4) << 3) + e;
            int co = c * 16 + (l & 15);
            float sum = 0.f;
            for (int o0 = lo_[0]; o0 <= hi_[0]; ++o0)
                for (int o1 = lo_[1]; o1 <= hi_[1]; ++o1)
                    for (int o2 = lo_[2]; o2 <= hi_[2]; ++o2) {
                        int k = (o0 + 1) * 9 + (o1 + 1) * 3 + (o2 + 1);
                        sum += W2[(size_t)k * 4096 + ci * 64 + co];
                    }
            unsigned short hi, lo;
            split2(sum, hi, lo);
            Wpk2h[(size_t)u * 8 + e] = hi;
            Wpk2l[(size_t)u * 8 + e] = lo;
        }
    }
}

// ---------------------------------------------------------------------------
__global__ void scatter_grid_kernel(const int* __restrict__ coords,
                                    unsigned short* __restrict__ grid, int n) {
    int i = blockIdx.x * blockDim.x + threadIdx.x;
    if (i < n)
        grid[(coords[3 * i] * D1 + coords[3 * i + 1]) * D1 + coords[3 * i + 2]] =
            (unsigned short)(i + 1);
}

// ---------------------------------------------------------------------------
// j-table builder (zero atomics; (i,k) and (i,s,d) are unique).
// jt1[(blk*27 + k)*64 + row] = j+1 ; jt2[((blk*8+s)*8+d)*64 + row] = j+1
// ---------------------------------------------------------------------------
__global__ void build_pairs_kernel(const int* __restrict__ coords,
                                   const unsigned short* __restrict__ grid,
                                   ushort_t* __restrict__ jt1,
                                   ushort_t* __restrict__ jt2, int n) {
    int i = blockIdx.x * blockDim.x + threadIdx.x;
    if (i >= n) return;
    int blk = i >> 6, row = i & 63;
    int c0 = coords[3 * i], cc1 = coords[3 * i + 1], cc2 = coords[3 * i + 2];

    int jv[27];
#pragma unroll
    for (int k = 0; k < 27; ++k) {
        int o0 = k / 9 - 1, o1 = (k / 3) % 3 - 1, o2 = k % 3 - 1;
        int x0 = c0 + o0, x1 = cc1 + o1, x2 = cc2 + o2;
        bool inb = (unsigned)x0 < D1 && (unsigned)x1 < D1 && (unsigned)x2 < D1;
        jv[k] = inb ? (int)grid[(x0 * D1 + x1) * D1 + x2] : 0;  // j+1 or 0
    }

#pragma unroll
    for (int k = 0; k < 27; ++k) {
        if (k == 13) continue;
        int j1 = jv[k];
        if (j1 == 0) continue;
        int o0 = k / 9 - 1, o1 = (k / 3) % 3 - 1, o2 = k % 3 - 1;
        jt1[((size_t)blk * 27 + k) * 64 + row] = (ushort_t)j1;
#pragma unroll
        for (int s = 0; s < 8; ++s) {
            int d0 = o0 + 1 - ((s >> 2) & 1);
            int d1 = o1 + 1 - ((s >> 1) & 1);
            int d2 = o2 + 1 - (s & 1);
            if (((d0 | d1 | d2) & ~1) == 0) {
                int d = (d0 << 2) | (d1 << 1) | d2;
                jt2[(((size_t)blk * 8 + s) * 8 + d) * 64 + row] = (ushort_t)j1;
            }
        }
    }
}

// ---------------------------------------------------------------------------
// One gathered-A MFMA pass: load (masked) A rows, hi/lo split, 6 MFMAs per
// col-tile accumulating into acc[4].
// ---------------------------------------------------------------------------
__device__ __forceinline__ void mfma_pass(bool has, int arow,
                                          const float* __restrict__ src,
                                          const short8_t* __restrict__ Bh,
                                          const short8_t* __restrict__ Bl,
                                          f32x4 acc[4], int lane) {
    const float* ap = src + (size_t)arow * 64 + ((lane >> 4) << 3);
    f32x4 z = {0.f, 0.f, 0.f, 0.f};
    f32x4 a0 = has ? *(const f32x4*)(ap) : z;
    f32x4 a1 = has ? *(const f32x4*)(ap + 4) : z;
    f32x4 a2 = has ? *(const f32x4*)(ap + 32) : z;
    f32x4 a3 = has ? *(const f32x4*)(ap + 36) : z;

    short8_t ah0, al0, ah1, al1;
#pragma unroll
    for (int e = 0; e < 4; ++e) {
        unsigned short hh, ll;
        split2(a0[e], hh, ll); ah0[e] = (short)hh; al0[e] = (short)ll;
        split2(a1[e], hh, ll); ah0[4 + e] = (short)hh; al0[4 + e] = (short)ll;
        split2(a2[e], hh, ll); ah1[e] = (short)hh; al1[e] = (short)ll;
        split2(a3[e], hh, ll); ah1[4 + e] = (short)hh; al1[4 + e] = (short)ll;
    }

#pragma unroll
    for (int c = 0; c < 4; ++c) {
        short8_t bh0 = Bh[c * 64 + lane];
        short8_t bl0 = Bl[c * 64 + lane];
        short8_t bh1 = Bh[(4 + c) * 64 + lane];
        short8_t bl1 = Bl[(4 + c) * 64 + lane];
        f32x4 a = acc[c];
        a = __builtin_amdgcn_mfma_f32_16x16x32_bf16(ah0, bh0, a, 0, 0, 0);
        a = __builtin_amdgcn_mfma_f32_16x16x32_bf16(al0, bh0, a, 0, 0, 0);
        a = __builtin_amdgcn_mfma_f32_16x16x32_bf16(ah0, bl0, a, 0, 0, 0);
        a = __builtin_amdgcn_mfma_f32_16x16x32_bf16(ah1, bh1, a, 0, 0, 0);
        a = __builtin_amdgcn_mfma_f32_16x16x32_bf16(al1, bh1, a, 0, 0, 0);
        a = __builtin_amdgcn_mfma_f32_16x16x32_bf16(ah1, bl1, a, 0, 0, 0);
        acc[c] = a;
    }
}

// ---------------------------------------------------------------------------
// conv1: 27 gathered MFMA passes (k=13 = dense self), acc in VGPRs,
// one barrier, SiLU + coalesced store.
// ---------------------------------------------------------------------------
__global__ __launch_bounds__(256) void conv1_fused_kernel(
    const float* __restrict__ feats, const unsigned short* __restrict__ Wpk1h,
    const unsigned short* __restrict__ Wpk1l, const float* __restrict__ b1,
    const ushort_t* __restrict__ jt1, float* __restrict__ h, int n) {
    __shared__ __align__(16) float oT[64 * OS];
    int base = blockIdx.x * 64;
    int t = threadIdx.x, w = t >> 6, lane = t & 63;
    int myrow = w * 16 + (lane & 15);

    f32x4 acc[4];
#pragma unroll
    for (int c = 0; c < 4; ++c) acc[c] = (f32x4){0.f, 0.f, 0.f, 0.f};

    const short8_t* Bh = (const short8_t*)Wpk1h;
    const short8_t* Bl = (const short8_t*)Wpk1l;
#pragma unroll 1
    for (int k = 0; k < 27; ++k) {
        int jv;
        if (k == 13)
            jv = (base + myrow < n) ? base + myrow + 1 : 0;
        else
            jv = jt1[((size_t)blockIdx.x * 27 + k) * 64 + myrow];
        bool has = jv > 0;
        if (__ballot(has) == 0ULL) continue;
        mfma_pass(has, has ? jv - 1 : 0, feats, Bh + (size_t)k * 512,
                  Bl + (size_t)k * 512, acc, lane);
    }

#pragma unroll
    for (int c = 0; c < 4; ++c) {
        int col = c * 16 + (lane & 15);
        float bb = b1[col];
#pragma unroll
        for (int r = 0; r < 4; ++r) {
            int row = w * 16 + ((lane >> 4) << 2) + r;
            oT[row * OS + col] = acc[c][r] + bb;
        }
    }
    __syncthreads();

    {   // SiLU + coalesced store
        int r = t >> 2, q0 = (t & 3) * 16;
        if (base + r < n) {
#pragma unroll
            for (int jj = 0; jj < 4; ++jj) {
                f32x4 v = *(f32x4*)&oT[r * OS + q0 + jj * 4];
#pragma unroll
                for (int u = 0; u < 4; ++u) v[u] = silu(v[u]);
                *(f32x4*)&h[(size_t)(base + r) * 64 + q0 + jj * 4] = v;
            }
        }
    }
}

// ---------------------------------------------------------------------------
// conv2: grid (nblk, 8). 8 gathered MFMA passes (d_self = 7-s uses j=i).
// ---------------------------------------------------------------------------
__global__ __launch_bounds__(256) void conv2_fused_kernel(
    const float* __restrict__ h, const unsigned short* __restrict__ Wpk2h,
    const unsigned short* __restrict__ Wpk2l, const float* __restrict__ b2,
    const ushort_t* __restrict__ jt2, float* __restrict__ out, int n) {
    __shared__ __align__(16) float oT[64 * OS];
    int base = blockIdx.x * 64, s = blockIdx.y;
    int t = threadIdx.x, w = t >> 6, lane = t & 63;
    int myrow = w * 16 + (lane & 15);
    int d_self = 7 - s;

    f32x4 acc[4];
#pragma unroll
    for (int c = 0; c < 4; ++c) acc[c] = (f32x4){0.f, 0.f, 0.f, 0.f};

    const short8_t* Bh = (const short8_t*)Wpk2h + (size_t)s * 8 * 512;
    const short8_t* Bl = (const short8_t*)Wpk2l + (size_t)s * 8 * 512;
#pragma unroll 1
    for (int d = 0; d < 8; ++d) {
        int jv;
        if (d == d_self)
            jv = (base + myrow < n) ? base + myrow + 1 : 0;
        else
            jv = jt2[(((size_t)blockIdx.x * 8 + s) * 8 + d) * 64 + myrow];
        bool has = jv > 0;
        if (__ballot(has) == 0ULL) continue;
        mfma_pass(has, has ? jv - 1 : 0, h, Bh + (size_t)d * 512,
                  Bl + (size_t)d * 512, acc, lane);
    }

#pragma unroll
    for (int c = 0; c < 4; ++c) {
        int col = c * 16 + (lane & 15);
        float bb = b2[col];
#pragma unroll
        for (int r = 0; r < 4; ++r) {
            int row = w * 16 + ((lane >> 4) << 2) + r;
            oT[row * OS + col] = acc[c][r] + bb;
        }
    }
    __syncthreads();

    {   // SiLU + coalesced store (regular stores; out row = parent*8 + s)
        int r = t >> 2, q0 = (t & 3) * 16;
        if (base + r < n) {
#pragma unroll
            for (int jj = 0; jj < 4; ++jj) {
                f32x4 v = *(f32x4*)&oT[r * OS + q0 + jj * 4];
#pragma unroll
                for (int u = 0; u < 4; ++u) v[u] = silu(v[u]);
                *(f32x4*)&out[((size_t)(base + r) * 8 + s) * 64 + q0 + jj * 4] = v;
            }
        }
    }
}

// ---------------------------------------------------------------------------
extern "C" void kernel_launch(void* const* d_in, const int* in_sizes, int n_in,
                              void* d_out, int out_size, void* d_ws,
                              size_t ws_size, hipStream_t stream) {
    const int* coords = (const int*)d_in[0];
    const float* feats = (const float*)d_in[1];
    const float* W1 = (const float*)d_in[2];
    const float* b1 = (const float*)d_in[3];
    const float* W2 = (const float*)d_in[4];
    const float* b2 = (const float*)d_in[5];
    float* out = (float*)d_out;

    int n = in_sizes[0] / 3;  // 20000
    int nblk = (n + 63) / 64; // 313

    char* ws = (char*)d_ws;
    size_t off = 0;
    auto alloc = [&](size_t bytes) {
        size_t o = off;
        off = (off + bytes + 255) & ~(size_t)255;
        return o;
    };
    unsigned short* grid1 = (unsigned short*)(ws + alloc((size_t)GRID_VOX * 2));
    float* h = (float*)(ws + alloc((size_t)n * 64 * 4));            // 5.12 MB
    unsigned short* Wpk1h = (unsigned short*)(ws + alloc(27 * 512 * 8 * 2));
    unsigned short* Wpk1l = (unsigned short*)(ws + alloc(27 * 512 * 8 * 2));
    unsigned short* Wpk2h = (unsigned short*)(ws + alloc(64 * 512 * 8 * 2));
    unsigned short* Wpk2l = (unsigned short*)(ws + alloc(64 * 512 * 8 * 2));
    size_t jt1Elems = (size_t)nblk * 27 * 64;
    size_t jt2Elems = (size_t)nblk * 64 * 64;  // 8 s * 8 d * 64 rows
    ushort_t* jt1 = (ushort_t*)(ws + alloc((jt1Elems + jt2Elems) * 2));
    ushort_t* jt2 = jt1 + jt1Elems;

    int njt16 = (int)(((jt1Elems + jt2Elems) * 2 + 15) / 16);
    int nzb = (njt16 + 255) / 256;
    int nfragblk = (27 * 512 + 64 * 512 + 255) / 256;  // 182

    setup_kernel<<<432 + nzb + nfragblk, 256, 0, stream>>>(
        W1, W2, (int4*)grid1, (int4*)jt1, njt16, nzb, Wpk1h, Wpk1l, Wpk2h,
        Wpk2l);
    scatter_grid_kernel<<<(n + 255) / 256, 256, 0, stream>>>(coords, grid1, n);
    build_pairs_kernel<<<(n + 255) / 256, 256, 0, stream>>>(coords, grid1, jt1,
                                                            jt2, n);

    conv1_fused_kernel<<<nblk, 256, 0, stream>>>(feats, Wpk1h, Wpk1l, b1, jt1,
                                                 h, n);
    conv2_fused_kernel<<<dim3(nblk, 8), 256, 0, stream>>>(h, Wpk2h, Wpk2l, b2,
                                                          jt2, out, n);
}

// Round 17
// 84.558 us; speedup vs baseline: 1.3873x; 1.2922x over previous
//
#include <hip/hip_runtime.h>

#define D1 96
#define GRID_VOX (D1 * D1 * D1)
#define CAP1 32   // per-voxel conv1 pairs (max 26 exact)
#define CAP2S 8   // per-(voxel,s) conv2 pairs (max 7 exact)
#define OS 68     // oT row stride in floats (bank-conflict pad, 16B aligned)

typedef __attribute__((ext_vector_type(8))) short short8_t;  // 8 bf16
typedef __attribute__((ext_vector_type(4))) float f32x4;

__device__ __forceinline__ unsigned short bf16rne(float x) {
    unsigned u = __float_as_uint(x);
    return (unsigned short)((u + 0x7FFF + ((u >> 16) & 1)) >> 16);
}
__device__ __forceinline__ void split2(float v, unsigned short& hi,
                                       unsigned short& lo) {
    hi = bf16rne(v);
    float hf = __uint_as_float((unsigned)hi << 16);
    lo = bf16rne(v - hf);
}
__device__ __forceinline__ float silu(float v) {
    return v / (1.f + __expf(-v));
}

// ---------------------------------------------------------------------------
// setup: blocks [0,432) zero grid; blocks [432,1474) pack MFMA B-fragments
// (bf16 hi/lo) and fold fp32 fixup weights.
// ---------------------------------------------------------------------------
__global__ void setup_kernel(const float* __restrict__ W1,
                             const float* __restrict__ W2,
                             int4* __restrict__ grid16,
                             unsigned short* __restrict__ Wpk1h,
                             unsigned short* __restrict__ Wpk1l,
                             unsigned short* __restrict__ Wpk2h,
                             unsigned short* __restrict__ Wpk2l,
                             float* __restrict__ W2e) {
    int b = blockIdx.x;
    if (b < 432) {
        grid16[b * 256 + threadIdx.x] = make_int4(0, 0, 0, 0);
        return;
    }
    int t = (b - 432) * 256 + threadIdx.x;
    if (t < 512) {  // conv1 B-fragments: W1[13] self tap
        int fid = t >> 6, l = t & 63;
        int kb = fid >> 2, c = fid & 3;
#pragma unroll
        for (int e = 0; e < 8; ++e) {
            int ci = kb * 32 + ((l >> 4) << 3) + e;
            int co = c * 16 + (l & 15);
            unsigned short hi, lo;
            split2(W1[13 * 4096 + ci * 64 + co], hi, lo);
            Wpk1h[(size_t)t * 8 + e] = hi;
            Wpk1l[(size_t)t * 8 + e] = lo;
        }
    } else if (t < 512 + 4096) {  // conv2 dense (self-parent fold) fragments
        int u = t - 512;
        int fid = u >> 6, l = u & 63;
        int s = fid >> 3, kb = (fid >> 2) & 1, c = fid & 3;
        int s0 = (s >> 2) & 1, s1 = (s >> 1) & 1, s2 = s & 1;
#pragma unroll
        for (int e = 0; e < 8; ++e) {
            int ci = kb * 32 + ((l >> 4) << 3) + e;
            int co = c * 16 + (l & 15);
            float sum = 0.f;
            for (int o0 = -s0; o0 <= 1 - s0; ++o0)
                for (int o1 = -s1; o1 <= 1 - s1; ++o1)
                    for (int o2 = -s2; o2 <= 1 - s2; ++o2) {
                        int k = (o0 + 1) * 9 + (o1 + 1) * 3 + (o2 + 1);
                        sum += W2[k * 4096 + ci * 64 + co];
                    }
            unsigned short hi, lo;
            split2(sum, hi, lo);
            Wpk2h[(size_t)u * 8 + e] = hi;
            Wpk2l[(size_t)u * 8 + e] = lo;
        }
    } else {  // W2e fp32 fixup weights
        int r = t - 4608;
        if (r >= 64 * 4096) return;
        int sd = r >> 12, e = r & 4095;
        int s = sd >> 3, d = sd & 7;
        int sa[3] = { (s >> 2) & 1, (s >> 1) & 1, s & 1 };
        int da[3] = { (d >> 2) & 1, (d >> 1) & 1, d & 1 };
        int lo_[3], hi_[3];
        for (int a = 0; a < 3; ++a) {
            int p = sa[a] - 1 + da[a];
            int l = 2 * p - sa[a];     if (l < -1) l = -1;
            int h = 2 * p + 1 - sa[a]; if (h > 1) h = 1;
            lo_[a] = l; hi_[a] = h;
        }
        float sum = 0.f;
        for (int o0 = lo_[0]; o0 <= hi_[0]; ++o0)
            for (int o1 = lo_[1]; o1 <= hi_[1]; ++o1)
                for (int o2 = lo_[2]; o2 <= hi_[2]; ++o2) {
                    int k = (o0 + 1) * 9 + (o1 + 1) * 3 + (o2 + 1);
                    sum += W2[k * 4096 + e];
                }
        W2e[(size_t)sd * 4096 + e] = sum;
    }
}

// ---------------------------------------------------------------------------
__global__ void scatter_grid_kernel(const int* __restrict__ coords,
                                    unsigned short* __restrict__ grid, int n) {
    int i = blockIdx.x * blockDim.x + threadIdx.x;
    if (i < n)
        grid[(coords[3 * i] * D1 + coords[3 * i + 1]) * D1 + coords[3 * i + 2]] =
            (unsigned short)(i + 1);
}

// ---------------------------------------------------------------------------
// Per-voxel pair builder (no atomics). conv1: j|(k<<17); conv2: j|(d<<17).
// ---------------------------------------------------------------------------
__global__ void build_pairs_kernel(const int* __restrict__ coords,
                                   const unsigned short* __restrict__ grid,
                                   int* __restrict__ c1, int* __restrict__ p1,
                                   int* __restrict__ c2s, int* __restrict__ p2s,
                                   int n) {
    int i = blockIdx.x * blockDim.x + threadIdx.x;
    if (i >= n) return;
    int c0 = coords[3 * i], cc1 = coords[3 * i + 1], cc2 = coords[3 * i + 2];

    int jv[27];
#pragma unroll
    for (int k = 0; k < 27; ++k) {
        int o0 = k / 9 - 1, o1 = (k / 3) % 3 - 1, o2 = k % 3 - 1;
        int x0 = c0 + o0, x1 = cc1 + o1, x2 = cc2 + o2;
        bool inb = (unsigned)x0 < D1 && (unsigned)x1 < D1 && (unsigned)x2 < D1;
        jv[k] = inb ? (int)grid[(x0 * D1 + x1) * D1 + x2] - 1 : -1;
    }

    int n1 = 0;
    int n2[8] = {0, 0, 0, 0, 0, 0, 0, 0};
#pragma unroll
    for (int k = 0; k < 27; ++k) {
        if (k == 13) continue;
        int j = jv[k];
        if (j < 0) continue;
        int o0 = k / 9 - 1, o1 = (k / 3) % 3 - 1, o2 = k % 3 - 1;
        p1[(size_t)i * CAP1 + n1] = j | (k << 17);
        ++n1;
#pragma unroll
        for (int s = 0; s < 8; ++s) {
            int d0 = o0 + 1 - ((s >> 2) & 1);
            int d1 = o1 + 1 - ((s >> 1) & 1);
            int d2 = o2 + 1 - (s & 1);
            if (((d0 | d1 | d2) & ~1) == 0) {
                int d = (d0 << 2) | (d1 << 1) | d2;
                p2s[((size_t)i * 8 + s) * CAP2S + n2[s]] = j | (d << 17);
                ++n2[s];
            }
        }
    }
    c1[i] = n1;
#pragma unroll
    for (int s = 0; s < 8; ++s) c2s[i * 8 + s] = n2[s];
}

// ---------------------------------------------------------------------------
__device__ __forceinline__ void load_split_A(const float* __restrict__ src,
                                             int arow, int lane, short8_t& ah0,
                                             short8_t& al0, short8_t& ah1,
                                             short8_t& al1) {
    const float* ap = src + (size_t)arow * 64 + ((lane >> 4) << 3);
    f32x4 a0 = *(const f32x4*)(ap);
    f32x4 a1 = *(const f32x4*)(ap + 4);
    f32x4 a2 = *(const f32x4*)(ap + 32);
    f32x4 a3 = *(const f32x4*)(ap + 36);
#pragma unroll
    for (int e = 0; e < 4; ++e) {
        unsigned short hh, ll;
        split2(a0[e], hh, ll); ah0[e] = (short)hh; al0[e] = (short)ll;
        split2(a1[e], hh, ll); ah0[4 + e] = (short)hh; al0[4 + e] = (short)ll;
        split2(a2[e], hh, ll); ah1[e] = (short)hh; al1[e] = (short)ll;
        split2(a3[e], hh, ll); ah1[4 + e] = (short)hh; al1[4 + e] = (short)ll;
    }
}

// ---------------------------------------------------------------------------
// 8-wave dense: wave w covers rows [(w&3)*16, +16) x col-tiles {2*(w>>2), +1}.
// 12 MFMAs per wave; +bias -> oT (stride OS).
// ---------------------------------------------------------------------------
__device__ __forceinline__ void dense_mfma8(const short8_t ah0, const short8_t al0,
                                            const short8_t ah1, const short8_t al1,
                                            const short8_t* __restrict__ Bh,
                                            const short8_t* __restrict__ Bl,
                                            const float* __restrict__ bias,
                                            float* __restrict__ oT, int w,
                                            int lane) {
    int c0 = (w >> 2) * 2;
#pragma unroll
    for (int cc = 0; cc < 2; ++cc) {
        int c = c0 + cc;
        short8_t bh0 = Bh[c * 64 + lane];
        short8_t bl0 = Bl[c * 64 + lane];
        short8_t bh1 = Bh[(4 + c) * 64 + lane];
        short8_t bl1 = Bl[(4 + c) * 64 + lane];
        f32x4 acc = {0.f, 0.f, 0.f, 0.f};
        acc = __builtin_amdgcn_mfma_f32_16x16x32_bf16(ah0, bh0, acc, 0, 0, 0);
        acc = __builtin_amdgcn_mfma_f32_16x16x32_bf16(al0, bh0, acc, 0, 0, 0);
        acc = __builtin_amdgcn_mfma_f32_16x16x32_bf16(ah0, bl0, acc, 0, 0, 0);
        acc = __builtin_amdgcn_mfma_f32_16x16x32_bf16(ah1, bh1, acc, 0, 0, 0);
        acc = __builtin_amdgcn_mfma_f32_16x16x32_bf16(al1, bh1, acc, 0, 0, 0);
        acc = __builtin_amdgcn_mfma_f32_16x16x32_bf16(ah1, bl1, acc, 0, 0, 0);
        int col = c * 16 + (lane & 15);
        float bb = bias[col];
#pragma unroll
        for (int r = 0; r < 4; ++r) {
            int row = (w & 3) * 16 + ((lane >> 4) << 2) + r;
            oT[row * OS + col] = acc[r] + bb;
        }
    }
}

// wave-scan helper (t<64): counts -> excl prefix + total, stored in LDS
__device__ __forceinline__ void scan64(int cnt, int lane, int* pfxs, int* cnts,
                                       int* nps) {
    int val = cnt;
#pragma unroll
    for (int off = 1; off < 64; off <<= 1) {
        int v2 = __shfl_up(val, off);
        if (lane >= off) val += v2;
    }
    pfxs[lane] = val - cnt;
    cnts[lane] = cnt;
    if (lane == 63) nps[0] = val;
}

// ---------------------------------------------------------------------------
// Barrier-free per-wave fixup loop (8 waves, stride 8; oT stride OS).
// ---------------------------------------------------------------------------
__device__ __forceinline__ void fixup_loop(const float* __restrict__ src,
                                           const float* __restrict__ Wbase,
                                           const int* __restrict__ pl, int np,
                                           float fsc[8][2][64],
                                           float* __restrict__ oT, int w,
                                           int lane) {
    int it = 0;
#pragma unroll 1
    for (int p = w; p < np; p += 8, ++it) {
        int e = pl[p];
        int j = e & 0x1FFFF, tag = (e >> 17) & 31, row = (e >> 23) & 63;
        float fv = src[(size_t)j * 64 + lane];  // coalesced 256B row
        int buf = it & 1;
        fsc[w][buf][lane] = fv;
        const float* wk = Wbase + (size_t)tag * 4096;  // [ci][co]
        float a0 = 0.f, a1 = 0.f, a2 = 0.f, a3 = 0.f;
#pragma unroll
        for (int c4 = 0; c4 < 16; ++c4) {
            f32x4 fb = *(f32x4*)&fsc[w][buf][c4 * 4];  // ds broadcast
            a0 += fb[0] * wk[(c4 * 4 + 0) * 64 + lane];
            a1 += fb[1] * wk[(c4 * 4 + 1) * 64 + lane];
            a2 += fb[2] * wk[(c4 * 4 + 2) * 64 + lane];
            a3 += fb[3] * wk[(c4 * 4 + 3) * 64 + lane];
        }
        atomicAdd(&oT[row * OS + lane], (a0 + a1) + (a2 + a3));
    }
}

// ---------------------------------------------------------------------------
// conv1 fused: 8 waves. dense MFMA ∥ scan -> compact -> fixups -> SiLU.
// ---------------------------------------------------------------------------
__global__ __launch_bounds__(512) void conv1_fused_kernel(
    const float* __restrict__ feats, const float* __restrict__ W1,
    const unsigned short* __restrict__ Wpk1h,
    const unsigned short* __restrict__ Wpk1l, const float* __restrict__ b1,
    const int* __restrict__ c1, const int* __restrict__ p1,
    float* __restrict__ h, int n) {
    __shared__ __align__(16) float oT[64 * OS];
    __shared__ __align__(16) float fsc[8][2][64];
    __shared__ int pl[1664];
    __shared__ int pfxs[64], cnts_s[64], nps[1];
    int base = blockIdx.x * 64;
    int t = threadIdx.x, w = t >> 6, lane = t & 63;

    if (t < 64) {
        int cnt = (base + lane < n) ? c1[base + lane] : 0;
        scan64(cnt, lane, pfxs, cnts_s, nps);
    }

    int arow = base + (w & 3) * 16 + (lane & 15);
    if (arow >= n) arow = n - 1;
    short8_t ah0, al0, ah1, al1;
    load_split_A(feats, arow, lane, ah0, al0, ah1, al1);
    dense_mfma8(ah0, al0, ah1, al1, (const short8_t*)Wpk1h,
                (const short8_t*)Wpk1l, b1, oT, w, lane);
    __syncthreads();

    {   // parallel compaction: 8 threads per row
        int row = t & 63, e0 = t >> 6;
        int cr = cnts_s[row], pf = pfxs[row];
        for (int e = e0; e < cr; e += 8)
            pl[pf + e] = p1[(size_t)(base + row) * CAP1 + e] | (row << 23);
    }
    __syncthreads();

    fixup_loop(feats, W1, pl, nps[0], fsc, oT, w, lane);
    __syncthreads();

    {   // SiLU + coalesced store (512 threads: 8 floats each)
        int r = t >> 3, c8 = (t & 7) * 8;
        if (base + r < n) {
#pragma unroll
            for (int jj = 0; jj < 2; ++jj) {
                f32x4 v = *(f32x4*)&oT[r * OS + c8 + jj * 4];
#pragma unroll
                for (int u = 0; u < 4; ++u) v[u] = silu(v[u]);
                *(f32x4*)&h[(size_t)(base + r) * 64 + c8 + jj * 4] = v;
            }
        }
    }
}

// ---------------------------------------------------------------------------
// conv2 fused: grid (313, 8), 8 waves. Same structure.
// ---------------------------------------------------------------------------
__global__ __launch_bounds__(512) void conv2_fused_kernel(
    const float* __restrict__ h, const unsigned short* __restrict__ Wpk2h,
    const unsigned short* __restrict__ Wpk2l, const float* __restrict__ W2e,
    const float* __restrict__ b2, const int* __restrict__ c2s,
    const int* __restrict__ p2s, float* __restrict__ out, int n) {
    __shared__ __align__(16) float oT[64 * OS];
    __shared__ __align__(16) float fsc[8][2][64];
    __shared__ int pl[448];
    __shared__ int pfxs[64], cnts_s[64], nps[1];
    int base = blockIdx.x * 64, s = blockIdx.y;
    int t = threadIdx.x, w = t >> 6, lane = t & 63;

    if (t < 64) {
        int cnt = (base + lane < n) ? c2s[(size_t)(base + lane) * 8 + s] : 0;
        scan64(cnt, lane, pfxs, cnts_s, nps);
    }

    int arow = base + (w & 3) * 16 + (lane & 15);
    if (arow >= n) arow = n - 1;
    short8_t ah0, al0, ah1, al1;
    load_split_A(h, arow, lane, ah0, al0, ah1, al1);
    dense_mfma8(ah0, al0, ah1, al1,
                (const short8_t*)Wpk2h + (size_t)s * 8 * 64,
                (const short8_t*)Wpk2l + (size_t)s * 8 * 64, b2, oT, w, lane);
    __syncthreads();

    {   // parallel compaction: 8 threads per row
        int row = t & 63, e0 = t >> 6;
        int cr = cnts_s[row], pf = pfxs[row];
        for (int e = e0; e < cr; e += 8)
            pl[pf + e] =
                p2s[((size_t)(base + row) * 8 + s) * CAP2S + e] | (row << 23);
    }
    __syncthreads();

    fixup_loop(h, W2e + (size_t)s * 8 * 4096, pl, nps[0], fsc, oT, w, lane);
    __syncthreads();

    {   // SiLU + coalesced store (out row = parent*8 + s)
        int r = t >> 3, c8 = (t & 7) * 8;
        if (base + r < n) {
#pragma unroll
            for (int jj = 0; jj < 2; ++jj) {
                f32x4 v = *(f32x4*)&oT[r * OS + c8 + jj * 4];
#pragma unroll
                for (int u = 0; u < 4; ++u) v[u] = silu(v[u]);
                *(f32x4*)&out[((size_t)(base + r) * 8 + s) * 64 + c8 + jj * 4] = v;
            }
        }
    }
}

// ---------------------------------------------------------------------------
extern "C" void kernel_launch(void* const* d_in, const int* in_sizes, int n_in,
                              void* d_out, int out_size, void* d_ws,
                              size_t ws_size, hipStream_t stream) {
    const int* coords = (const int*)d_in[0];
    const float* feats = (const float*)d_in[1];
    const float* W1 = (const float*)d_in[2];
    const float* b1 = (const float*)d_in[3];
    const float* W2 = (const float*)d_in[4];
    const float* b2 = (const float*)d_in[5];
    float* out = (float*)d_out;

    int n = in_sizes[0] / 3;  // 20000
    int nblk = (n + 63) / 64; // 313

    char* ws = (char*)d_ws;
    size_t off = 0;
    auto alloc = [&](size_t bytes) {
        size_t o = off;
        off = (off + bytes + 255) & ~(size_t)255;
        return o;
    };
    unsigned short* grid1 = (unsigned short*)(ws + alloc((size_t)GRID_VOX * 2));
    float* h      = (float*)(ws + alloc((size_t)n * 64 * 4));     // 5.12 MB
    float* W2e    = (float*)(ws + alloc(64 * 4096 * 4));          // 1 MB
    unsigned short* Wpk1h = (unsigned short*)(ws + alloc(512 * 8 * 2));
    unsigned short* Wpk1l = (unsigned short*)(ws + alloc(512 * 8 * 2));
    unsigned short* Wpk2h = (unsigned short*)(ws + alloc(4096 * 8 * 2));
    unsigned short* Wpk2l = (unsigned short*)(ws + alloc(4096 * 8 * 2));
    int*   c1     = (int*)(ws + alloc((size_t)n * 9 * 4));        // c1[n]+c2s[8n]
    int*   c2s    = c1 + n;
    int*   p1     = (int*)(ws + alloc((size_t)n * CAP1 * 4));     // 2.56 MB
    int*   p2s    = (int*)(ws + alloc((size_t)n * 8 * CAP2S * 4)); // 5.12 MB

    setup_kernel<<<1474, 256, 0, stream>>>(W1, W2, (int4*)grid1, Wpk1h, Wpk1l,
                                           Wpk2h, Wpk2l, W2e);
    scatter_grid_kernel<<<(n + 255) / 256, 256, 0, stream>>>(coords, grid1, n);
    build_pairs_kernel<<<(n + 255) / 256, 256, 0, stream>>>(
        coords, grid1, c1, p1, c2s, p2s, n);

    conv1_fused_kernel<<<nblk, 512, 0, stream>>>(feats, W1, Wpk1h, Wpk1l, b1,
                                                 c1, p1, h, n);
    conv2_fused_kernel<<<dim3(nblk, 8), 512, 0, stream>>>(
        h, Wpk2h, Wpk2l, W2e, b2, c2s, p2s, out, n);
}

// Round 18
// 83.417 us; speedup vs baseline: 1.4063x; 1.0137x over previous
//
#include <hip/hip_runtime.h>

#define D1 96
#define GRID_VOX (D1 * D1 * D1)
#define CAP2S 8   // per-(voxel,s) conv2 pairs (max 7 exact)
#define OS 68     // oT row stride in floats (bank-conflict pad, 16B aligned)

typedef __attribute__((ext_vector_type(8))) short short8_t;  // 8 bf16
typedef __attribute__((ext_vector_type(4))) float f32x4;

__device__ __forceinline__ unsigned short bf16rne(float x) {
    unsigned u = __float_as_uint(x);
    return (unsigned short)((u + 0x7FFF + ((u >> 16) & 1)) >> 16);
}
__device__ __forceinline__ void split2(float v, unsigned short& hi,
                                       unsigned short& lo) {
    hi = bf16rne(v);
    float hf = __uint_as_float((unsigned)hi << 16);
    lo = bf16rne(v - hf);
}
__device__ __forceinline__ float silu(float v) {
    return v / (1.f + __expf(-v));
}

// ---------------------------------------------------------------------------
// setup: one kernel, disjoint thread ranges (no ordering deps):
//  [0,512)            pack conv1 self-tap B-fragments (bf16 hi/lo)
//  [512,4608)         pack conv2 per-child folded B-fragments
//  [4608,266752)      fold fp32 conv2 fixup weights W2e
//  [266752,266752+n)  scatter grid[cell] = i+1   (NO zero-fill needed:
//                     readers validate entries via exact coords match)
// ---------------------------------------------------------------------------
__global__ void setup_kernel(const float* __restrict__ W1,
                             const float* __restrict__ W2,
                             const int* __restrict__ coords,
                             unsigned short* __restrict__ grid,
                             unsigned short* __restrict__ Wpk1h,
                             unsigned short* __restrict__ Wpk1l,
                             unsigned short* __restrict__ Wpk2h,
                             unsigned short* __restrict__ Wpk2l,
                             float* __restrict__ W2e, int n) {
    int t = blockIdx.x * blockDim.x + threadIdx.x;
    if (t < 512) {  // conv1 B-fragments: W1[13] self tap
        int fid = t >> 6, l = t & 63;
        int kb = fid >> 2, c = fid & 3;
#pragma unroll
        for (int e = 0; e < 8; ++e) {
            int ci = kb * 32 + ((l >> 4) << 3) + e;
            int co = c * 16 + (l & 15);
            unsigned short hi, lo;
            split2(W1[13 * 4096 + ci * 64 + co], hi, lo);
            Wpk1h[(size_t)t * 8 + e] = hi;
            Wpk1l[(size_t)t * 8 + e] = lo;
        }
    } else if (t < 4608) {  // conv2 dense (self-parent fold) fragments
        int u = t - 512;
        int fid = u >> 6, l = u & 63;
        int s = fid >> 3, kb = (fid >> 2) & 1, c = fid & 3;
        int s0 = (s >> 2) & 1, s1 = (s >> 1) & 1, s2 = s & 1;
#pragma unroll
        for (int e = 0; e < 8; ++e) {
            int ci = kb * 32 + ((l >> 4) << 3) + e;
            int co = c * 16 + (l & 15);
            float sum = 0.f;
            for (int o0 = -s0; o0 <= 1 - s0; ++o0)
                for (int o1 = -s1; o1 <= 1 - s1; ++o1)
                    for (int o2 = -s2; o2 <= 1 - s2; ++o2) {
                        int k = (o0 + 1) * 9 + (o1 + 1) * 3 + (o2 + 1);
                        sum += W2[k * 4096 + ci * 64 + co];
                    }
            unsigned short hi, lo;
            split2(sum, hi, lo);
            Wpk2h[(size_t)u * 8 + e] = hi;
            Wpk2l[(size_t)u * 8 + e] = lo;
        }
    } else if (t < 4608 + 262144) {  // W2e fp32 fixup weights
        int r = t - 4608;
        int sd = r >> 12, e = r & 4095;
        int s = sd >> 3, d = sd & 7;
        int sa[3] = { (s >> 2) & 1, (s >> 1) & 1, s & 1 };
        int da[3] = { (d >> 2) & 1, (d >> 1) & 1, d & 1 };
        int lo_[3], hi_[3];
        for (int a = 0; a < 3; ++a) {
            int p = sa[a] - 1 + da[a];
            int l = 2 * p - sa[a];     if (l < -1) l = -1;
            int h = 2 * p + 1 - sa[a]; if (h > 1) h = 1;
            lo_[a] = l; hi_[a] = h;
        }
        float sum = 0.f;
        for (int o0 = lo_[0]; o0 <= hi_[0]; ++o0)
            for (int o1 = lo_[1]; o1 <= hi_[1]; ++o1)
                for (int o2 = lo_[2]; o2 <= hi_[2]; ++o2) {
                    int k = (o0 + 1) * 9 + (o1 + 1) * 3 + (o2 + 1);
                    sum += W2[k * 4096 + e];
                }
        W2e[(size_t)sd * 4096 + e] = sum;
    } else {  // scatter
        int i = t - (4608 + 262144);
        if (i < n)
            grid[(coords[3 * i] * D1 + coords[3 * i + 1]) * D1 +
                 coords[3 * i + 2]] = (unsigned short)(i + 1);
    }
}

// ---------------------------------------------------------------------------
__device__ __forceinline__ void load_split_A(const float* __restrict__ src,
                                             int arow, int lane, short8_t& ah0,
                                             short8_t& al0, short8_t& ah1,
                                             short8_t& al1) {
    const float* ap = src + (size_t)arow * 64 + ((lane >> 4) << 3);
    f32x4 a0 = *(const f32x4*)(ap);
    f32x4 a1 = *(const f32x4*)(ap + 4);
    f32x4 a2 = *(const f32x4*)(ap + 32);
    f32x4 a3 = *(const f32x4*)(ap + 36);
#pragma unroll
    for (int e = 0; e < 4; ++e) {
        unsigned short hh, ll;
        split2(a0[e], hh, ll); ah0[e] = (short)hh; al0[e] = (short)ll;
        split2(a1[e], hh, ll); ah0[4 + e] = (short)hh; al0[4 + e] = (short)ll;
        split2(a2[e], hh, ll); ah1[e] = (short)hh; al1[e] = (short)ll;
        split2(a3[e], hh, ll); ah1[4 + e] = (short)hh; al1[4 + e] = (short)ll;
    }
}

// ---------------------------------------------------------------------------
// 8-wave dense: wave w covers rows [(w&3)*16, +16) x col-tiles {2*(w>>2), +1}.
// ---------------------------------------------------------------------------
__device__ __forceinline__ void dense_mfma8(const short8_t ah0, const short8_t al0,
                                            const short8_t ah1, const short8_t al1,
                                            const short8_t* __restrict__ Bh,
                                            const short8_t* __restrict__ Bl,
                                            const float* __restrict__ bias,
                                            float* __restrict__ oT, int w,
                                            int lane) {
    int c0 = (w >> 2) * 2;
#pragma unroll
    for (int cc = 0; cc < 2; ++cc) {
        int c = c0 + cc;
        short8_t bh0 = Bh[c * 64 + lane];
        short8_t bl0 = Bl[c * 64 + lane];
        short8_t bh1 = Bh[(4 + c) * 64 + lane];
        short8_t bl1 = Bl[(4 + c) * 64 + lane];
        f32x4 acc = {0.f, 0.f, 0.f, 0.f};
        acc = __builtin_amdgcn_mfma_f32_16x16x32_bf16(ah0, bh0, acc, 0, 0, 0);
        acc = __builtin_amdgcn_mfma_f32_16x16x32_bf16(al0, bh0, acc, 0, 0, 0);
        acc = __builtin_amdgcn_mfma_f32_16x16x32_bf16(ah0, bl0, acc, 0, 0, 0);
        acc = __builtin_amdgcn_mfma_f32_16x16x32_bf16(ah1, bh1, acc, 0, 0, 0);
        acc = __builtin_amdgcn_mfma_f32_16x16x32_bf16(al1, bh1, acc, 0, 0, 0);
        acc = __builtin_amdgcn_mfma_f32_16x16x32_bf16(ah1, bl1, acc, 0, 0, 0);
        int col = c * 16 + (lane & 15);
        float bb = bias[col];
#pragma unroll
        for (int r = 0; r < 4; ++r) {
            int row = (w & 3) * 16 + ((lane >> 4) << 2) + r;
            oT[row * OS + col] = acc[r] + bb;
        }
    }
}

// wave-scan helper (wave 0): counts -> excl prefix + total, stored in LDS
__device__ __forceinline__ void scan64(int cnt, int lane, int* pfxs, int* cnts,
                                       int* nps) {
    int val = cnt;
#pragma unroll
    for (int off = 1; off < 64; off <<= 1) {
        int v2 = __shfl_up(val, off);
        if (lane >= off) val += v2;
    }
    pfxs[lane] = val - cnt;
    cnts[lane] = cnt;
    if (lane == 63) nps[0] = val;
}

// ---------------------------------------------------------------------------
// Barrier-free per-wave fixup loop (8 waves, stride 8; oT stride OS).
// ---------------------------------------------------------------------------
__device__ __forceinline__ void fixup_loop(const float* __restrict__ src,
                                           const float* __restrict__ Wbase,
                                           const int* __restrict__ pl, int np,
                                           float fsc[8][2][64],
                                           float* __restrict__ oT, int w,
                                           int lane) {
    int it = 0;
#pragma unroll 1
    for (int p = w; p < np; p += 8, ++it) {
        int e = pl[p];
        int j = e & 0x1FFFF, tag = (e >> 17) & 31, row = (e >> 23) & 63;
        float fv = src[(size_t)j * 64 + lane];  // coalesced 256B row
        int buf = it & 1;
        fsc[w][buf][lane] = fv;
        const float* wk = Wbase + (size_t)tag * 4096;  // [ci][co]
        float a0 = 0.f, a1 = 0.f, a2 = 0.f, a3 = 0.f;
#pragma unroll
        for (int c4 = 0; c4 < 16; ++c4) {
            f32x4 fb = *(f32x4*)&fsc[w][buf][c4 * 4];  // ds broadcast
            a0 += fb[0] * wk[(c4 * 4 + 0) * 64 + lane];
            a1 += fb[1] * wk[(c4 * 4 + 1) * 64 + lane];
            a2 += fb[2] * wk[(c4 * 4 + 2) * 64 + lane];
            a3 += fb[3] * wk[(c4 * 4 + 3) * 64 + lane];
        }
        atomicAdd(&oT[row * OS + lane], (a0 + a1) + (a2 + a3));
    }
}

// ---------------------------------------------------------------------------
// conv1 fused, 8 waves: threads 0..63 inline-build pair lists (validated grid
// reads; conv1 pairs -> LDS, conv2 pairs -> global c2s/p2s), all threads do
// dense MFMA, then compact -> fixups -> SiLU.
// ---------------------------------------------------------------------------
__global__ __launch_bounds__(512) void conv1_fused_kernel(
    const int* __restrict__ coords, const float* __restrict__ feats,
    const float* __restrict__ W1, const unsigned short* __restrict__ Wpk1h,
    const unsigned short* __restrict__ Wpk1l, const float* __restrict__ b1,
    const unsigned short* __restrict__ grid, int* __restrict__ c2s,
    int* __restrict__ p2s, float* __restrict__ h, int n) {
    __shared__ __align__(16) float oT[64 * OS];
    __shared__ __align__(16) float fsc[8][2][64];
    __shared__ int plt[64 * 26];
    __shared__ int pl[1664];
    __shared__ int pfxs[64], cnts_s[64], nps[1];
    int base = blockIdx.x * 64;
    int t = threadIdx.x, w = t >> 6, lane = t & 63;

    // ---- inline pair build (threads 0..63 = wave 0), validated grid reads
    if (t < 64) {
        int myv = base + t;
        int cnt = 0;
        if (myv < n) {
            int c0 = coords[3 * myv], c1v = coords[3 * myv + 1],
                c2v = coords[3 * myv + 2];
            int n2[8] = {0, 0, 0, 0, 0, 0, 0, 0};
#pragma unroll 1
            for (int g = 0; g < 3; ++g) {
                int jv9[9];
                int kb = g * 9;
#pragma unroll
                for (int u = 0; u < 9; ++u) {
                    int k = kb + u;
                    int o0 = k / 9 - 1, o1 = (k / 3) % 3 - 1, o2 = k % 3 - 1;
                    int x0 = c0 + o0, x1 = c1v + o1, x2 = c2v + o2;
                    bool inb = (unsigned)x0 < D1 && (unsigned)x1 < D1 &&
                               (unsigned)x2 < D1;
                    jv9[u] = inb ? (int)grid[(x0 * D1 + x1) * D1 + x2] : 0;
                }
#pragma unroll
                for (int u = 0; u < 9; ++u) {
                    int k = kb + u;
                    if (k == 13) continue;
                    int j1 = jv9[u];
                    if (j1 < 1 || j1 > n) continue;  // poison/garbage reject
                    int o0 = k / 9 - 1, o1 = (k / 3) % 3 - 1, o2 = k % 3 - 1;
                    int x0 = c0 + o0, x1 = c1v + o1, x2 = c2v + o2;
                    int jj = j1 - 1;
                    // exact validation: passes iff jj truly sits at this cell
                    if (coords[3 * jj] != x0 || coords[3 * jj + 1] != x1 ||
                        coords[3 * jj + 2] != x2)
                        continue;
                    plt[t * 26 + cnt] = jj | (k << 17);
                    ++cnt;
#pragma unroll
                    for (int s = 0; s < 8; ++s) {
                        int d0 = o0 + 1 - ((s >> 2) & 1);
                        int d1 = o1 + 1 - ((s >> 1) & 1);
                        int d2 = o2 + 1 - (s & 1);
                        if (((d0 | d1 | d2) & ~1) == 0) {
                            int d = (d0 << 2) | (d1 << 1) | d2;
                            p2s[((size_t)myv * 8 + s) * CAP2S + n2[s]] =
                                jj | (d << 17);
                            ++n2[s];
                        }
                    }
                }
            }
#pragma unroll
            for (int s = 0; s < 8; ++s) c2s[myv * 8 + s] = n2[s];
        }
        scan64(cnt, lane, pfxs, cnts_s, nps);
    }

    // ---- dense (all 8 waves)
    int arow = base + (w & 3) * 16 + (lane & 15);
    if (arow >= n) arow = n - 1;
    short8_t ah0, al0, ah1, al1;
    load_split_A(feats, arow, lane, ah0, al0, ah1, al1);
    dense_mfma8(ah0, al0, ah1, al1, (const short8_t*)Wpk1h,
                (const short8_t*)Wpk1l, b1, oT, w, lane);
    __syncthreads();

    {   // parallel compaction: 8 threads per row
        int row = t & 63, e0 = t >> 6;
        int cr = cnts_s[row], pf = pfxs[row];
        for (int e = e0; e < cr; e += 8)
            pl[pf + e] = plt[row * 26 + e] | (row << 23);
    }
    __syncthreads();

    fixup_loop(feats, W1, pl, nps[0], fsc, oT, w, lane);
    __syncthreads();

    {   // SiLU + coalesced store
        int r = t >> 3, c8 = (t & 7) * 8;
        if (base + r < n) {
#pragma unroll
            for (int jj = 0; jj < 2; ++jj) {
                f32x4 v = *(f32x4*)&oT[r * OS + c8 + jj * 4];
#pragma unroll
                for (int u = 0; u < 4; ++u) v[u] = silu(v[u]);
                *(f32x4*)&h[(size_t)(base + r) * 64 + c8 + jj * 4] = v;
            }
        }
    }
}

// ---------------------------------------------------------------------------
// conv2 fused: grid (313, 8), 8 waves (unchanged round-17 structure).
// ---------------------------------------------------------------------------
__global__ __launch_bounds__(512) void conv2_fused_kernel(
    const float* __restrict__ h, const unsigned short* __restrict__ Wpk2h,
    const unsigned short* __restrict__ Wpk2l, const float* __restrict__ W2e,
    const float* __restrict__ b2, const int* __restrict__ c2s,
    const int* __restrict__ p2s, float* __restrict__ out, int n) {
    __shared__ __align__(16) float oT[64 * OS];
    __shared__ __align__(16) float fsc[8][2][64];
    __shared__ int pl[448];
    __shared__ int pfxs[64], cnts_s[64], nps[1];
    int base = blockIdx.x * 64, s = blockIdx.y;
    int t = threadIdx.x, w = t >> 6, lane = t & 63;

    if (t < 64) {
        int cnt = (base + lane < n) ? c2s[(size_t)(base + lane) * 8 + s] : 0;
        scan64(cnt, lane, pfxs, cnts_s, nps);
    }

    int arow = base + (w & 3) * 16 + (lane & 15);
    if (arow >= n) arow = n - 1;
    short8_t ah0, al0, ah1, al1;
    load_split_A(h, arow, lane, ah0, al0, ah1, al1);
    dense_mfma8(ah0, al0, ah1, al1,
                (const short8_t*)Wpk2h + (size_t)s * 8 * 64,
                (const short8_t*)Wpk2l + (size_t)s * 8 * 64, b2, oT, w, lane);
    __syncthreads();

    {   // parallel compaction: 8 threads per row
        int row = t & 63, e0 = t >> 6;
        int cr = cnts_s[row], pf = pfxs[row];
        for (int e = e0; e < cr; e += 8)
            pl[pf + e] =
                p2s[((size_t)(base + row) * 8 + s) * CAP2S + e] | (row << 23);
    }
    __syncthreads();

    fixup_loop(h, W2e + (size_t)s * 8 * 4096, pl, nps[0], fsc, oT, w, lane);
    __syncthreads();

    {   // SiLU + coalesced store (out row = parent*8 + s)
        int r = t >> 3, c8 = (t & 7) * 8;
        if (base + r < n) {
#pragma unroll
            for (int jj = 0; jj < 2; ++jj) {
                f32x4 v = *(f32x4*)&oT[r * OS + c8 + jj * 4];
#pragma unroll
                for (int u = 0; u < 4; ++u) v[u] = silu(v[u]);
                *(f32x4*)&out[((size_t)(base + r) * 8 + s) * 64 + c8 + jj * 4] = v;
            }
        }
    }
}

// ---------------------------------------------------------------------------
extern "C" void kernel_launch(void* const* d_in, const int* in_sizes, int n_in,
                              void* d_out, int out_size, void* d_ws,
                              size_t ws_size, hipStream_t stream) {
    const int* coords = (const int*)d_in[0];
    const float* feats = (const float*)d_in[1];
    const float* W1 = (const float*)d_in[2];
    const float* b1 = (const float*)d_in[3];
    const float* W2 = (const float*)d_in[4];
    const float* b2 = (const float*)d_in[5];
    float* out = (float*)d_out;

    int n = in_sizes[0] / 3;  // 20000
    int nblk = (n + 63) / 64; // 313

    char* ws = (char*)d_ws;
    size_t off = 0;
    auto alloc = [&](size_t bytes) {
        size_t o = off;
        off = (off + bytes + 255) & ~(size_t)255;
        return o;
    };
    unsigned short* grid1 = (unsigned short*)(ws + alloc((size_t)GRID_VOX * 2));
    float* h      = (float*)(ws + alloc((size_t)n * 64 * 4));     // 5.12 MB
    float* W2e    = (float*)(ws + alloc(64 * 4096 * 4));          // 1 MB
    unsigned short* Wpk1h = (unsigned short*)(ws + alloc(512 * 8 * 2));
    unsigned short* Wpk1l = (unsigned short*)(ws + alloc(512 * 8 * 2));
    unsigned short* Wpk2h = (unsigned short*)(ws + alloc(4096 * 8 * 2));
    unsigned short* Wpk2l = (unsigned short*)(ws + alloc(4096 * 8 * 2));
    int*   c2s    = (int*)(ws + alloc((size_t)n * 8 * 4));        // 0.64 MB
    int*   p2s    = (int*)(ws + alloc((size_t)n * 8 * CAP2S * 4)); // 5.12 MB

    // setup (pack weights + fold W2e + scatter grid; no zero-fill needed)
    int totalT = 4608 + 262144 + n;
    setup_kernel<<<(totalT + 255) / 256, 256, 0, stream>>>(
        W1, W2, coords, grid1, Wpk1h, Wpk1l, Wpk2h, Wpk2l, W2e, n);

    conv1_fused_kernel<<<nblk, 512, 0, stream>>>(coords, feats, W1, Wpk1h,
                                                 Wpk1l, b1, grid1, c2s, p2s, h,
                                                 n);
    conv2_fused_kernel<<<dim3(nblk, 8), 512, 0, stream>>>(
        h, Wpk2h, Wpk2l, W2e, b2, c2s, p2s, out, n);
}

// Round 19
// 82.162 us; speedup vs baseline: 1.4278x; 1.0153x over previous
//
#include <hip/hip_runtime.h>

#define D1 96
#define GRID_VOX (D1 * D1 * D1)
#define CAP2S 8   // per-(voxel,s) conv2 pairs (max 7 exact)
#define OS 68     // oT row stride in floats (bank-conflict pad, 16B aligned)

typedef __attribute__((ext_vector_type(8))) short short8_t;  // 8 bf16
typedef __attribute__((ext_vector_type(4))) float f32x4;

__device__ __forceinline__ unsigned short bf16rne(float x) {
    unsigned u = __float_as_uint(x);
    return (unsigned short)((u + 0x7FFF + ((u >> 16) & 1)) >> 16);
}
__device__ __forceinline__ void split2(float v, unsigned short& hi,
                                       unsigned short& lo) {
    hi = bf16rne(v);
    float hf = __uint_as_float((unsigned)hi << 16);
    lo = bf16rne(v - hf);
}
__device__ __forceinline__ float silu(float v) {
    return v / (1.f + __expf(-v));
}

// ---------------------------------------------------------------------------
// setup: one kernel, disjoint thread ranges (no ordering deps):
//  [0,512)            pack conv1 self-tap B-fragments (bf16 hi/lo)
//  [512,4608)         pack conv2 per-child folded B-fragments
//  [4608,266752)      fold fp32 conv2 fixup weights W2e
//  [266752,266752+n)  scatter grid[cell] = i+1  (no zero-fill: readers
//                     validate entries via exact coords match)
// ---------------------------------------------------------------------------
__global__ void setup_kernel(const float* __restrict__ W1,
                             const float* __restrict__ W2,
                             const int* __restrict__ coords,
                             unsigned short* __restrict__ grid,
                             unsigned short* __restrict__ Wpk1h,
                             unsigned short* __restrict__ Wpk1l,
                             unsigned short* __restrict__ Wpk2h,
                             unsigned short* __restrict__ Wpk2l,
                             float* __restrict__ W2e, int n) {
    int t = blockIdx.x * blockDim.x + threadIdx.x;
    if (t < 512) {  // conv1 B-fragments: W1[13] self tap
        int fid = t >> 6, l = t & 63;
        int kb = fid >> 2, c = fid & 3;
#pragma unroll
        for (int e = 0; e < 8; ++e) {
            int ci = kb * 32 + ((l >> 4) << 3) + e;
            int co = c * 16 + (l & 15);
            unsigned short hi, lo;
            split2(W1[13 * 4096 + ci * 64 + co], hi, lo);
            Wpk1h[(size_t)t * 8 + e] = hi;
            Wpk1l[(size_t)t * 8 + e] = lo;
        }
    } else if (t < 4608) {  // conv2 dense (self-parent fold) fragments
        int u = t - 512;
        int fid = u >> 6, l = u & 63;
        int s = fid >> 3, kb = (fid >> 2) & 1, c = fid & 3;
        int s0 = (s >> 2) & 1, s1 = (s >> 1) & 1, s2 = s & 1;
#pragma unroll
        for (int e = 0; e < 8; ++e) {
            int ci = kb * 32 + ((l >> 4) << 3) + e;
            int co = c * 16 + (l & 15);
            float sum = 0.f;
            for (int o0 = -s0; o0 <= 1 - s0; ++o0)
                for (int o1 = -s1; o1 <= 1 - s1; ++o1)
                    for (int o2 = -s2; o2 <= 1 - s2; ++o2) {
                        int k = (o0 + 1) * 9 + (o1 + 1) * 3 + (o2 + 1);
                        sum += W2[k * 4096 + ci * 64 + co];
                    }
            unsigned short hi, lo;
            split2(sum, hi, lo);
            Wpk2h[(size_t)u * 8 + e] = hi;
            Wpk2l[(size_t)u * 8 + e] = lo;
        }
    } else if (t < 4608 + 262144) {  // W2e fp32 fixup weights
        int r = t - 4608;
        int sd = r >> 12, e = r & 4095;
        int s = sd >> 3, d = sd & 7;
        int sa[3] = { (s >> 2) & 1, (s >> 1) & 1, s & 1 };
        int da[3] = { (d >> 2) & 1, (d >> 1) & 1, d & 1 };
        int lo_[3], hi_[3];
        for (int a = 0; a < 3; ++a) {
            int p = sa[a] - 1 + da[a];
            int l = 2 * p - sa[a];     if (l < -1) l = -1;
            int h = 2 * p + 1 - sa[a]; if (h > 1) h = 1;
            lo_[a] = l; hi_[a] = h;
        }
        float sum = 0.f;
        for (int o0 = lo_[0]; o0 <= hi_[0]; ++o0)
            for (int o1 = lo_[1]; o1 <= hi_[1]; ++o1)
                for (int o2 = lo_[2]; o2 <= hi_[2]; ++o2) {
                    int k = (o0 + 1) * 9 + (o1 + 1) * 3 + (o2 + 1);
                    sum += W2[k * 4096 + e];
                }
        W2e[(size_t)sd * 4096 + e] = sum;
    } else {  // scatter
        int i = t - (4608 + 262144);
        if (i < n)
            grid[(coords[3 * i] * D1 + coords[3 * i + 1]) * D1 +
                 coords[3 * i + 2]] = (unsigned short)(i + 1);
    }
}

// ---------------------------------------------------------------------------
__device__ __forceinline__ void load_split_A(const float* __restrict__ src,
                                             int arow, int lane, short8_t& ah0,
                                             short8_t& al0, short8_t& ah1,
                                             short8_t& al1) {
    const float* ap = src + (size_t)arow * 64 + ((lane >> 4) << 3);
    f32x4 a0 = *(const f32x4*)(ap);
    f32x4 a1 = *(const f32x4*)(ap + 4);
    f32x4 a2 = *(const f32x4*)(ap + 32);
    f32x4 a3 = *(const f32x4*)(ap + 36);
#pragma unroll
    for (int e = 0; e < 4; ++e) {
        unsigned short hh, ll;
        split2(a0[e], hh, ll); ah0[e] = (short)hh; al0[e] = (short)ll;
        split2(a1[e], hh, ll); ah0[4 + e] = (short)hh; al0[4 + e] = (short)ll;
        split2(a2[e], hh, ll); ah1[e] = (short)hh; al1[e] = (short)ll;
        split2(a3[e], hh, ll); ah1[4 + e] = (short)hh; al1[4 + e] = (short)ll;
    }
}

// ---------------------------------------------------------------------------
// 8-wave dense: wave w covers rows [(w&3)*16, +16) x col-tiles {2*(w>>2), +1}.
// ---------------------------------------------------------------------------
__device__ __forceinline__ void dense_mfma8(const short8_t ah0, const short8_t al0,
                                            const short8_t ah1, const short8_t al1,
                                            const short8_t* __restrict__ Bh,
                                            const short8_t* __restrict__ Bl,
                                            const float* __restrict__ bias,
                                            float* __restrict__ oT, int w,
                                            int lane) {
    int c0 = (w >> 2) * 2;
#pragma unroll
    for (int cc = 0; cc < 2; ++cc) {
        int c = c0 + cc;
        short8_t bh0 = Bh[c * 64 + lane];
        short8_t bl0 = Bl[c * 64 + lane];
        short8_t bh1 = Bh[(4 + c) * 64 + lane];
        short8_t bl1 = Bl[(4 + c) * 64 + lane];
        f32x4 acc = {0.f, 0.f, 0.f, 0.f};
        acc = __builtin_amdgcn_mfma_f32_16x16x32_bf16(ah0, bh0, acc, 0, 0, 0);
        acc = __builtin_amdgcn_mfma_f32_16x16x32_bf16(al0, bh0, acc, 0, 0, 0);
        acc = __builtin_amdgcn_mfma_f32_16x16x32_bf16(ah0, bl0, acc, 0, 0, 0);
        acc = __builtin_amdgcn_mfma_f32_16x16x32_bf16(ah1, bh1, acc, 0, 0, 0);
        acc = __builtin_amdgcn_mfma_f32_16x16x32_bf16(al1, bh1, acc, 0, 0, 0);
        acc = __builtin_amdgcn_mfma_f32_16x16x32_bf16(ah1, bl1, acc, 0, 0, 0);
        int col = c * 16 + (lane & 15);
        float bb = bias[col];
#pragma unroll
        for (int r = 0; r < 4; ++r) {
            int row = (w & 3) * 16 + ((lane >> 4) << 2) + r;
            oT[row * OS + col] = acc[r] + bb;
        }
    }
}

// wave-scan helper (wave 0): counts -> excl prefix + total, stored in LDS
__device__ __forceinline__ void scan64(int cnt, int lane, int* pfxs, int* cnts,
                                       int* nps) {
    int val = cnt;
#pragma unroll
    for (int off = 1; off < 64; off <<= 1) {
        int v2 = __shfl_up(val, off);
        if (lane >= off) val += v2;
    }
    pfxs[lane] = val - cnt;
    cnts[lane] = cnt;
    if (lane == 63) nps[0] = val;
}

// ---------------------------------------------------------------------------
// Barrier-free per-wave fixup loop (8 waves, stride 8; oT stride OS).
// ---------------------------------------------------------------------------
__device__ __forceinline__ void fixup_loop(const float* __restrict__ src,
                                           const float* __restrict__ Wbase,
                                           const int* __restrict__ pl, int np,
                                           float fsc[8][2][64],
                                           float* __restrict__ oT, int w,
                                           int lane) {
    int it = 0;
#pragma unroll 1
    for (int p = w; p < np; p += 8, ++it) {
        int e = pl[p];
        int j = e & 0x1FFFF, tag = (e >> 17) & 31, row = (e >> 23) & 63;
        float fv = src[(size_t)j * 64 + lane];  // coalesced 256B row
        int buf = it & 1;
        fsc[w][buf][lane] = fv;
        const float* wk = Wbase + (size_t)tag * 4096;  // [ci][co]
        float a0 = 0.f, a1 = 0.f, a2 = 0.f, a3 = 0.f;
#pragma unroll
        for (int c4 = 0; c4 < 16; ++c4) {
            f32x4 fb = *(f32x4*)&fsc[w][buf][c4 * 4];  // ds broadcast
            a0 += fb[0] * wk[(c4 * 4 + 0) * 64 + lane];
            a1 += fb[1] * wk[(c4 * 4 + 1) * 64 + lane];
            a2 += fb[2] * wk[(c4 * 4 + 2) * 64 + lane];
            a3 += fb[3] * wk[(c4 * 4 + 3) * 64 + lane];
        }
        atomicAdd(&oT[row * OS + lane], (a0 + a1) + (a2 + a3));
    }
}

// ---------------------------------------------------------------------------
// conv1 fused, 8 waves: threads 0..63 inline-build pair lists (validated grid
// reads; conv1 pairs -> LDS, conv2 pairs -> global c2s/p2s), all threads do
// dense MFMA, then compact -> fixups -> SiLU.
// ---------------------------------------------------------------------------
__global__ __launch_bounds__(512) void conv1_fused_kernel(
    const int* __restrict__ coords, const float* __restrict__ feats,
    const float* __restrict__ W1, const unsigned short* __restrict__ Wpk1h,
    const unsigned short* __restrict__ Wpk1l, const float* __restrict__ b1,
    const unsigned short* __restrict__ grid, int* __restrict__ c2s,
    int* __restrict__ p2s, float* __restrict__ h, int n) {
    __shared__ __align__(16) float oT[64 * OS];
    __shared__ __align__(16) float fsc[8][2][64];
    __shared__ int plt[64 * 26];
    __shared__ int pl[1664];
    __shared__ int pfxs[64], cnts_s[64], nps[1];
    int base = blockIdx.x * 64;
    int t = threadIdx.x, w = t >> 6, lane = t & 63;

    // ---- inline pair build (threads 0..63 = wave 0), validated grid reads
    if (t < 64) {
        int myv = base + t;
        int cnt = 0;
        if (myv < n) {
            int c0 = coords[3 * myv], c1v = coords[3 * myv + 1],
                c2v = coords[3 * myv + 2];
            int n2[8] = {0, 0, 0, 0, 0, 0, 0, 0};
#pragma unroll 1
            for (int g = 0; g < 3; ++g) {
                int jv9[9];
                int kb = g * 9;
#pragma unroll
                for (int u = 0; u < 9; ++u) {
                    int k = kb + u;
                    int o0 = k / 9 - 1, o1 = (k / 3) % 3 - 1, o2 = k % 3 - 1;
                    int x0 = c0 + o0, x1 = c1v + o1, x2 = c2v + o2;
                    bool inb = (unsigned)x0 < D1 && (unsigned)x1 < D1 &&
                               (unsigned)x2 < D1;
                    jv9[u] = inb ? (int)grid[(x0 * D1 + x1) * D1 + x2] : 0;
                }
#pragma unroll
                for (int u = 0; u < 9; ++u) {
                    int k = kb + u;
                    if (k == 13) continue;
                    int j1 = jv9[u];
                    if (j1 < 1 || j1 > n) continue;  // poison/garbage reject
                    int o0 = k / 9 - 1, o1 = (k / 3) % 3 - 1, o2 = k % 3 - 1;
                    int x0 = c0 + o0, x1 = c1v + o1, x2 = c2v + o2;
                    int jj = j1 - 1;
                    // exact validation: passes iff jj truly sits at this cell
                    if (coords[3 * jj] != x0 || coords[3 * jj + 1] != x1 ||
                        coords[3 * jj + 2] != x2)
                        continue;
                    plt[t * 26 + cnt] = jj | (k << 17);
                    ++cnt;
#pragma unroll
                    for (int s = 0; s < 8; ++s) {
                        int d0 = o0 + 1 - ((s >> 2) & 1);
                        int d1 = o1 + 1 - ((s >> 1) & 1);
                        int d2 = o2 + 1 - (s & 1);
                        if (((d0 | d1 | d2) & ~1) == 0) {
                            int d = (d0 << 2) | (d1 << 1) | d2;
                            p2s[((size_t)myv * 8 + s) * CAP2S + n2[s]] =
                                jj | (d << 17);
                            ++n2[s];
                        }
                    }
                }
            }
#pragma unroll
            for (int s = 0; s < 8; ++s) c2s[myv * 8 + s] = n2[s];
        }
        scan64(cnt, lane, pfxs, cnts_s, nps);
    }

    // ---- dense (all 8 waves)
    int arow = base + (w & 3) * 16 + (lane & 15);
    if (arow >= n) arow = n - 1;
    short8_t ah0, al0, ah1, al1;
    load_split_A(feats, arow, lane, ah0, al0, ah1, al1);
    dense_mfma8(ah0, al0, ah1, al1, (const short8_t*)Wpk1h,
                (const short8_t*)Wpk1l, b1, oT, w, lane);
    __syncthreads();

    {   // parallel compaction: 8 threads per row
        int row = t & 63, e0 = t >> 6;
        int cr = cnts_s[row], pf = pfxs[row];
        for (int e = e0; e < cr; e += 8)
            pl[pf + e] = plt[row * 26 + e] | (row << 23);
    }
    __syncthreads();

    fixup_loop(feats, W1, pl, nps[0], fsc, oT, w, lane);
    __syncthreads();

    {   // SiLU + coalesced store
        int r = t >> 3, c8 = (t & 7) * 8;
        if (base + r < n) {
#pragma unroll
            for (int jj = 0; jj < 2; ++jj) {
                f32x4 v = *(f32x4*)&oT[r * OS + c8 + jj * 4];
#pragma unroll
                for (int u = 0; u < 4; ++u) v[u] = silu(v[u]);
                *(f32x4*)&h[(size_t)(base + r) * 64 + c8 + jj * 4] = v;
            }
        }
    }
}

// ---------------------------------------------------------------------------
// conv2 fused: 1D grid 2560 with XCD tile-affinity swizzle. Decode puts all 8
// s-children of tile T on the same idx%8 (same XCD): the 16KB h-tile is
// fetched into ONE L2, fixup gathers hit it warm, and the tile's 8 blocks
// write one contiguous 128KB out range.
//   Tm = idx%8; s = (idx/8)%8; T = (idx/64)*8 + Tm
// ---------------------------------------------------------------------------
__global__ __launch_bounds__(512) void conv2_fused_kernel(
    const float* __restrict__ h, const unsigned short* __restrict__ Wpk2h,
    const unsigned short* __restrict__ Wpk2l, const float* __restrict__ W2e,
    const float* __restrict__ b2, const int* __restrict__ c2s,
    const int* __restrict__ p2s, float* __restrict__ out, int n) {
    __shared__ __align__(16) float oT[64 * OS];
    __shared__ __align__(16) float fsc[8][2][64];
    __shared__ int pl[448];
    __shared__ int pfxs[64], cnts_s[64], nps[1];
    int idx = blockIdx.x;
    int Tm = idx & 7, s = (idx >> 3) & 7, T = (idx >> 6) * 8 + Tm;
    int base = T * 64;
    if (base >= n) return;
    int t = threadIdx.x, w = t >> 6, lane = t & 63;

    if (t < 64) {
        int cnt = (base + lane < n) ? c2s[(size_t)(base + lane) * 8 + s] : 0;
        scan64(cnt, lane, pfxs, cnts_s, nps);
    }

    int arow = base + (w & 3) * 16 + (lane & 15);
    if (arow >= n) arow = n - 1;
    short8_t ah0, al0, ah1, al1;
    load_split_A(h, arow, lane, ah0, al0, ah1, al1);
    dense_mfma8(ah0, al0, ah1, al1,
                (const short8_t*)Wpk2h + (size_t)s * 8 * 64,
                (const short8_t*)Wpk2l + (size_t)s * 8 * 64, b2, oT, w, lane);
    __syncthreads();

    {   // parallel compaction: 8 threads per row
        int row = t & 63, e0 = t >> 6;
        int cr = cnts_s[row], pf = pfxs[row];
        for (int e = e0; e < cr; e += 8)
            pl[pf + e] =
                p2s[((size_t)(base + row) * 8 + s) * CAP2S + e] | (row << 23);
    }
    __syncthreads();

    fixup_loop(h, W2e + (size_t)s * 8 * 4096, pl, nps[0], fsc, oT, w, lane);
    __syncthreads();

    {   // SiLU + coalesced store (out row = parent*8 + s)
        int r = t >> 3, c8 = (t & 7) * 8;
        if (base + r < n) {
#pragma unroll
            for (int jj = 0; jj < 2; ++jj) {
                f32x4 v = *(f32x4*)&oT[r * OS + c8 + jj * 4];
#pragma unroll
                for (int u = 0; u < 4; ++u) v[u] = silu(v[u]);
                *(f32x4*)&out[((size_t)(base + r) * 8 + s) * 64 + c8 + jj * 4] = v;
            }
        }
    }
}

// ---------------------------------------------------------------------------
extern "C" void kernel_launch(void* const* d_in, const int* in_sizes, int n_in,
                              void* d_out, int out_size, void* d_ws,
                              size_t ws_size, hipStream_t stream) {
    const int* coords = (const int*)d_in[0];
    const float* feats = (const float*)d_in[1];
    const float* W1 = (const float*)d_in[2];
    const float* b1 = (const float*)d_in[3];
    const float* W2 = (const float*)d_in[4];
    const float* b2 = (const float*)d_in[5];
    float* out = (float*)d_out;

    int n = in_sizes[0] / 3;  // 20000
    int nblk = (n + 63) / 64; // 313

    char* ws = (char*)d_ws;
    size_t off = 0;
    auto alloc = [&](size_t bytes) {
        size_t o = off;
        off = (off + bytes + 255) & ~(size_t)255;
        return o;
    };
    unsigned short* grid1 = (unsigned short*)(ws + alloc((size_t)GRID_VOX * 2));
    float* h      = (float*)(ws + alloc((size_t)n * 64 * 4));     // 5.12 MB
    float* W2e    = (float*)(ws + alloc(64 * 4096 * 4));          // 1 MB
    unsigned short* Wpk1h = (unsigned short*)(ws + alloc(512 * 8 * 2));
    unsigned short* Wpk1l = (unsigned short*)(ws + alloc(512 * 8 * 2));
    unsigned short* Wpk2h = (unsigned short*)(ws + alloc(4096 * 8 * 2));
    unsigned short* Wpk2l = (unsigned short*)(ws + alloc(4096 * 8 * 2));
    int*   c2s    = (int*)(ws + alloc((size_t)n * 8 * 4));        // 0.64 MB
    int*   p2s    = (int*)(ws + alloc((size_t)n * 8 * CAP2S * 4)); // 5.12 MB

    // setup (pack weights + fold W2e + scatter grid; no zero-fill needed)
    int totalT = 4608 + 262144 + n;
    setup_kernel<<<(totalT + 255) / 256, 256, 0, stream>>>(
        W1, W2, coords, grid1, Wpk1h, Wpk1l, Wpk2h, Wpk2l, W2e, n);

    conv1_fused_kernel<<<nblk, 512, 0, stream>>>(coords, feats, W1, Wpk1h,
                                                 Wpk1l, b1, grid1, c2s, p2s, h,
                                                 n);
    int nTileGrp = (nblk + 7) / 8;  // 40
    conv2_fused_kernel<<<nTileGrp * 64, 512, 0, stream>>>(
        h, Wpk2h, Wpk2l, W2e, b2, c2s, p2s, out, n);
}